// Round 3
// baseline (277.016 us; speedup 1.0000x reference)
//
#include <hip/hip_runtime.h>
#include <hip/hip_bf16.h>
#include <math.h>

#define N 8192
#define D 1024
#define BM 256
#define BK 64
#define NTIL 32                         // 8192/256
#define NBLK 528                        // 32*33/2 lower-tri tiles
#define ITERS 8                         // 16 K-tiles / 2 per iteration

typedef __bf16 bf16_t;
typedef bf16_t bf16x4 __attribute__((ext_vector_type(4)));
typedef bf16_t bf16x8 __attribute__((ext_vector_type(8)));
typedef float f32x4 __attribute__((ext_vector_type(4)));

// ---------------------------------------------------------------------------
// Kernel 1: L2-normalize each row of the fp32 embeddings, cast to bf16.
// Also zeroes sumExp/posSum for this row (replaces the memset dispatch).
// ---------------------------------------------------------------------------
__global__ __launch_bounds__(256) void norm_cast(const float* __restrict__ in,
                                                 bf16_t* __restrict__ out,
                                                 float* __restrict__ sumExp,
                                                 float* __restrict__ posSum) {
    const int row = blockIdx.x;
    const int tid = threadIdx.x;
    if (tid == 0) { sumExp[row] = 0.f; posSum[row] = 0.f; }
    const float4 v = ((const float4*)(in + (size_t)row * D))[tid];
    float ss = v.x * v.x + v.y * v.y + v.z * v.z + v.w * v.w;
    #pragma unroll
    for (int off = 32; off >= 1; off >>= 1) ss += __shfl_xor(ss, off, 64);
    __shared__ float red[4];
    const int wave = tid >> 6, lane = tid & 63;
    if (lane == 0) red[wave] = ss;
    __syncthreads();
    const float tot = red[0] + red[1] + red[2] + red[3];
    const float scale = 1.0f / fmaxf(sqrtf(tot), 1e-12f);
    bf16x4 o;
    o[0] = (bf16_t)(v.x * scale);
    o[1] = (bf16_t)(v.y * scale);
    o[2] = (bf16_t)(v.z * scale);
    o[3] = (bf16_t)(v.w * scale);
    ((bf16x4*)(out + (size_t)row * D))[tid] = o;
}

// ---------------------------------------------------------------------------
// Kernel 2: fused symmetric  C = E·E^T / T -> exp -> masked row+col sums.
// 256x256 tiles, BK=64, **16 waves (4M x 4N, 1024 threads)** for 4 waves/SIMD,
// 8-phase schedule (2 K-tiles/iter), counted vmcnt(2) at phases 4/8,
// double-buffered LDS = exactly 128 KiB. Per-wave output 64x64 (acc = 64 regs)
// so the whole wave state fits the 128-reg budget that 4 waves/SIMD demands.
// LDS swizzle: physical 16B unit = logical ^ (row&7); staging keeps the LDS
// destination linear (global_load_lds requirement) and inverse-permutes the
// GLOBAL source address; frag reads apply the same XOR.
// ---------------------------------------------------------------------------
__global__ __launch_bounds__(1024, 4) void gemm_fused(const bf16_t* __restrict__ E,
                                                      const int* __restrict__ labels,
                                                      float* __restrict__ sumExp,
                                                      float* __restrict__ posSum) {
    __shared__ bf16_t As[2][2][128 * 64];   // [buf][half(rows 0-127 / 128-255)][...]
    __shared__ bf16_t Bs[2][2][128 * 64];   // [buf][half(cols 0-127 / 128-255)][...]
    // total static LDS: 131072 B

    // XCD-aware bijective swizzle (528 % 8 == 0)
    const int b0 = blockIdx.x;
    const int b  = (b0 & 7) * (NBLK / 8) + (b0 >> 3);

    // triangular decode: b -> (ti >= tj)
    int ti = (int)((sqrtf(8.0f * (float)b + 1.0f) - 1.0f) * 0.5f);
    while ((ti + 1) * (ti + 2) / 2 <= b) ++ti;
    while (ti * (ti + 1) / 2 > b) --ti;
    const int tj = b - ti * (ti + 1) / 2;
    const bool isDiag = (ti == tj);

    const int tid  = threadIdx.x;
    const int wave = tid >> 6;
    const int lane = tid & 63;
    const int lr   = lane & 15;
    const int q    = lane >> 4;
    const int wm   = wave >> 2;     // 0..3 : 64-row strip
    const int wn   = wave & 3;      // 0..3 : 64-col strip
    const int rowStart = ti * BM;
    const int colStart = tj * BM;

    f32x4 acc[4][4];
    #pragma unroll
    for (int m = 0; m < 4; ++m)
        #pragma unroll
        for (int n = 0; n < 4; ++n) acc[m][n] = {0.f, 0.f, 0.f, 0.f};

    // ---- staging geometry: 1024 threads x 16 B = one 128x64 half-tile per
    // single global_load_lds. phys unit u = tid -> row r=u>>3, logical unit
    // (u&7)^(r&7) (inverse-swizzled global source, linear LDS dest).
    const int r0  = tid >> 3;                    // 0..127
    const int lu0 = (tid & 7) ^ (r0 & 7);
    const char* gA = (const char*)(E + (size_t)rowStart * D) + (size_t)r0 * (D * 2) + lu0 * 16;
    const char* gB = (const char*)(E + (size_t)colStart * D) + (size_t)r0 * (D * 2) + lu0 * 16;

    #define STAGE_A(buf, h, kb) do {                                                     \
        const char* g_ = gA + (size_t)(h) * (128 * 2048) + (kb);                         \
        char* l_ = (char*)&As[buf][h][0] + wave * 1024;                                  \
        __builtin_amdgcn_global_load_lds((const __attribute__((address_space(1))) void*)g_, \
            (__attribute__((address_space(3))) void*)l_, 16, 0, 0);                      \
    } while (0)
    #define STAGE_B(buf, h, kb) do {                                                     \
        const char* g_ = gB + (size_t)(h) * (128 * 2048) + (kb);                         \
        char* l_ = (char*)&Bs[buf][h][0] + wave * 1024;                                  \
        __builtin_amdgcn_global_load_lds((const __attribute__((address_space(1))) void*)g_, \
            (__attribute__((address_space(3))) void*)l_, 16, 0, 0);                      \
    } while (0)

    // ---- frag-read bases. Wave wm reads A rows wm*64 + m*16 + lr -> half
    // wm>>1, row-in-half (wm&1)*64 + m*16 + lr. Logical unit u0 = k*4+q,
    // phys = u0 ^ (lr&7) (row offsets are multiples of 8, XOR term unchanged).
    const int su0 = ((0 + q) ^ (lane & 7)) * 16;     // k = 0
    const int su1 = ((4 + q) ^ (lane & 7)) * 16;     // k = 1
    const char* rA0 = (const char*)&As[0][wm >> 1][0] + ((wm & 1) * 64 + lr) * 128;
    const char* rA1 = (const char*)&As[1][wm >> 1][0] + ((wm & 1) * 64 + lr) * 128;
    const char* rB0 = (const char*)&Bs[0][wn >> 1][0] + ((wn & 1) * 64 + lr) * 128;
    const char* rB1 = (const char*)&Bs[1][wn >> 1][0] + ((wn & 1) * 64 + lr) * 128;

    #define LD4(DST, RBASE, SU) do {                                                     \
        _Pragma("unroll")                                                                \
        for (int i_ = 0; i_ < 4; ++i_)                                                   \
            DST[i_] = *(const bf16x8*)((RBASE) + i_ * 2048 + (SU));                      \
    } while (0)
    // 8 MFMAs: m0-3 x n-pair {NB, NB+1}
    #define MFMA8(AF, BF, NB) do {                                                       \
        _Pragma("unroll")                                                                \
        for (int m_ = 0; m_ < 4; ++m_) {                                                 \
            _Pragma("unroll")                                                            \
            for (int n_ = 0; n_ < 2; ++n_)                                               \
                acc[m_][(NB) + n_] = __builtin_amdgcn_mfma_f32_16x16x32_bf16(            \
                    AF[m_], BF[(NB) + n_], acc[m_][(NB) + n_], 0, 0, 0);                 \
        }                                                                                \
    } while (0)
    #define PHASE_MID() do {                                                             \
        __builtin_amdgcn_s_barrier();                                                    \
        asm volatile("s_waitcnt lgkmcnt(0)");                                            \
        __builtin_amdgcn_sched_barrier(0);                                               \
        __builtin_amdgcn_s_setprio(1);                                                   \
    } while (0)
    #define PHASE_END() do {                                                             \
        __builtin_amdgcn_s_setprio(0);                                                   \
        __builtin_amdgcn_s_barrier();                                                    \
    } while (0)

    bf16x8 af[4], bf0[4], bf1[4];   // af reloaded per k-half (liveness ph1-2 / ph3-4)

    // ---- prologue: buf0 (K-tile 0) fully + buf1.B (K-tile 1). 6 loads;
    // vmcnt(2) -> buf0's 4 landed, buf1.B's 2 stay in flight.
    STAGE_B(0, 0, 0);  STAGE_B(0, 1, 0);
    STAGE_A(0, 0, 0);  STAGE_A(0, 1, 0);
    STAGE_B(1, 0, 128); STAGE_B(1, 1, 128);
    asm volatile("s_waitcnt vmcnt(2)" ::: "memory");
    __builtin_amdgcn_sched_barrier(0);
    __builtin_amdgcn_s_barrier();

    #pragma unroll 1
    for (int it = 0; it < ITERS; ++it) {
        const bool lastIt = (it == ITERS - 1);
        const int kb1 = (2 * it + 1) * 128;   // buf1's K-tile (byte col offset)
        const int kb2 = (2 * it + 2) * 128;   // next buf0 K-tile
        const int kb3 = (2 * it + 3) * 128;   // next buf1 K-tile

        // phase 1: buf0 k0, n01 | stage buf1.A h0
        LD4(af,  rA0, su0);
        LD4(bf0, rB0, su0);
        STAGE_A(1, 0, kb1);
        PHASE_MID();
        MFMA8(af, bf0, 0);
        PHASE_END();

        // phase 2: buf0 k0, n23 | read buf0 B k1 | stage buf1.A h1
        LD4(bf1, rB0, su1);
        STAGE_A(1, 1, kb1);
        PHASE_MID();
        MFMA8(af, bf0, 2);
        PHASE_END();

        // phase 3: buf0 k1, n01 | read buf0 A k1 | stage buf0.B h0 (WAR ok: B reads ended ph2)
        LD4(af, rA0, su1);
        if (!lastIt) STAGE_B(0, 0, kb2);
        PHASE_MID();
        MFMA8(af, bf1, 0);
        PHASE_END();

        // phase 4: buf0 k1, n23 | stage buf0.B h1 | counted vmcnt:
        // outstanding 6 = {B1h0,B1h1 (prev ph7/8)} {A1h0,A1h1 (ph1/2)} {B0'h0,B0'h1}
        // vmcnt(2) drains the oldest 4 = buf1 complete before ph5 reads.
        if (!lastIt) {
            STAGE_B(0, 1, kb2);
            asm volatile("s_waitcnt vmcnt(2)" ::: "memory");
        } else {
            asm volatile("s_waitcnt vmcnt(0)" ::: "memory");
        }
        __builtin_amdgcn_sched_barrier(0);
        PHASE_MID();
        MFMA8(af, bf1, 2);
        PHASE_END();

        // phase 5: buf1 k0, n01 | stage buf0.A h0 (WAR ok: A reads ended ph3)
        LD4(af,  rA1, su0);
        LD4(bf0, rB1, su0);
        if (!lastIt) STAGE_A(0, 0, kb2);
        PHASE_MID();
        MFMA8(af, bf0, 0);
        PHASE_END();

        // phase 6: buf1 k0, n23 | read buf1 B k1 | stage buf0.A h1
        LD4(bf1, rB1, su1);
        if (!lastIt) STAGE_A(0, 1, kb2);
        PHASE_MID();
        MFMA8(af, bf0, 2);
        PHASE_END();

        // phase 7: buf1 k1, n01 | read buf1 A k1 | stage buf1.B h0 (WAR ok: B reads ended ph6)
        LD4(af, rA1, su1);
        if (!lastIt) STAGE_B(1, 0, kb3);
        PHASE_MID();
        MFMA8(af, bf1, 0);
        PHASE_END();

        // phase 8: buf1 k1, n23 | stage buf1.B h1 | counted vmcnt(2):
        // drains {B0'h0,B0'h1,A0'h0,A0'h1} -> buf0 ready for next iter.
        if (!lastIt) {
            STAGE_B(1, 1, kb3);
            asm volatile("s_waitcnt vmcnt(2)" ::: "memory");
            __builtin_amdgcn_sched_barrier(0);
        }
        PHASE_MID();
        MFMA8(af, bf1, 2);
        PHASE_END();
    }

    // ---- epilogue: C/D layout col=lane&15, row=q*4+e (m89/m91).
    // Labels read straight from global (L2-resident, once per block).
    const float invT = 1.0f / 0.07f;
    int lc[4];
    #pragma unroll
    for (int n = 0; n < 4; ++n)
        lc[n] = labels[colStart + wn * 64 + n * 16 + lr];

    float colAll[4] = {0.f, 0.f, 0.f, 0.f};
    float colPos[4] = {0.f, 0.f, 0.f, 0.f};
    #pragma unroll
    for (int m = 0; m < 4; ++m) {
        #pragma unroll
        for (int e = 0; e < 4; ++e) {
            const int rloc = wm * 64 + m * 16 + q * 4 + e;
            const int gi   = rowStart + rloc;
            const int li   = labels[gi];
            float s_all = 0.f, s_pos = 0.f;
            #pragma unroll
            for (int n = 0; n < 4; ++n) {
                const int cloc = wn * 64 + n * 16 + lr;
                const int gj   = colStart + cloc;
                const float v  = __expf(acc[m][n][e] * invT);
                const bool same = (lc[n] == li);
                s_all += v;
                if (same && gi != gj) s_pos += v;
                if (!isDiag) {            // wave-uniform branch
                    colAll[n] += v;       // gi != gj guaranteed off-diagonal
                    if (same) colPos[n] += v;
                }
            }
            #pragma unroll
            for (int off = 1; off < 16; off <<= 1) {
                s_all += __shfl_xor(s_all, off, 64);
                s_pos += __shfl_xor(s_pos, off, 64);
            }
            if (lr == 0) {
                atomicAdd(&sumExp[gi], s_all);
                atomicAdd(&posSum[gi], s_pos);
            }
        }
    }
    if (!isDiag) {
        #pragma unroll
        for (int n = 0; n < 4; ++n) {
            float a = colAll[n], p = colPos[n];
            a += __shfl_xor(a, 16, 64);  a += __shfl_xor(a, 32, 64);
            p += __shfl_xor(p, 16, 64);  p += __shfl_xor(p, 32, 64);
            if (q == 0) {
                const int gj = colStart + wn * 64 + n * 16 + lr;
                atomicAdd(&sumExp[gj], a);
                atomicAdd(&posSum[gj], p);
            }
        }
    }
}

// ---------------------------------------------------------------------------
// Kernel 3: loss_i = log(sumExp_i / posSum_i); out = mean(loss).
// ---------------------------------------------------------------------------
__global__ __launch_bounds__(1024) void finalize(const float* __restrict__ sumExp,
                                                 const float* __restrict__ posSum,
                                                 float* __restrict__ out) {
    const int tid = threadIdx.x;
    float s = 0.f;
    #pragma unroll
    for (int i = tid; i < N; i += 1024)
        s += __logf(sumExp[i] / posSum[i]);
    #pragma unroll
    for (int off = 32; off >= 1; off >>= 1) s += __shfl_xor(s, off, 64);
    __shared__ float red[16];
    if ((tid & 63) == 0) red[tid >> 6] = s;
    __syncthreads();
    if (tid == 0) {
        float t = 0.f;
        #pragma unroll
        for (int i = 0; i < 16; ++i) t += red[i];
        out[0] = t / (float)N;
    }
}

extern "C" void kernel_launch(void* const* d_in, const int* in_sizes, int n_in,
                              void* d_out, int out_size, void* d_ws, size_t ws_size,
                              hipStream_t stream) {
    const float* emb    = (const float*)d_in[0];
    const int*   labels = (const int*)d_in[1];
    float* out = (float*)d_out;

    // ws layout: [sumExp: N floats][posSum: N floats][EN: N*D bf16]
    float*  sumExp = (float*)d_ws;
    float*  posSum = sumExp + N;
    bf16_t* EN     = (bf16_t*)((char*)d_ws + (size_t)2 * N * sizeof(float));

    norm_cast<<<N, 256, 0, stream>>>(emb, EN, sumExp, posSum);

    gemm_fused<<<NBLK, 1024, 0, stream>>>(EN, labels, sumExp, posSum);

    finalize<<<1, 1024, 0, stream>>>(sumExp, posSum, out);
}

// Round 4
// 229.129 us; speedup vs baseline: 1.2090x; 1.2090x over previous
//
#include <hip/hip_runtime.h>
#include <hip/hip_bf16.h>
#include <math.h>

#define N 8192
#define D 1024
#define BM 256
#define BK 32
#define NTIL 32                         // 8192/256
#define NBLK 528                        // 32*33/2 lower-tri tiles
#define KSTEPS 32                       // 1024/32
#define BUFSZ 16384                     // 256*32*2B per panel buffer

typedef __bf16 bf16_t;
typedef bf16_t bf16x4 __attribute__((ext_vector_type(4)));
typedef bf16_t bf16x8 __attribute__((ext_vector_type(8)));
typedef float f32x4 __attribute__((ext_vector_type(4)));

// ---------------------------------------------------------------------------
// Kernel 1: L2-normalize each row, cast to bf16. Wave-per-row (no LDS, no
// __syncthreads). Also zeroes sumExp/posSum (replaces the memset dispatch).
// ---------------------------------------------------------------------------
__global__ __launch_bounds__(256) void norm_cast(const float* __restrict__ in,
                                                 bf16_t* __restrict__ out,
                                                 float* __restrict__ sumExp,
                                                 float* __restrict__ posSum) {
    const int wave = threadIdx.x >> 6, lane = threadIdx.x & 63;
    const int row  = blockIdx.x * 4 + wave;
    const float4* src = (const float4*)(in + (size_t)row * D);
    float4 v[4];
    float ss = 0.f;
    #pragma unroll
    for (int i = 0; i < 4; ++i) {
        v[i] = src[lane + 64 * i];
        ss += v[i].x * v[i].x + v[i].y * v[i].y + v[i].z * v[i].z + v[i].w * v[i].w;
    }
    #pragma unroll
    for (int off = 32; off >= 1; off >>= 1) ss += __shfl_xor(ss, off, 64);
    const float scale = 1.0f / fmaxf(sqrtf(ss), 1e-12f);
    bf16x4* dst = (bf16x4*)(out + (size_t)row * D);
    #pragma unroll
    for (int i = 0; i < 4; ++i) {
        bf16x4 o;
        o[0] = (bf16_t)(v[i].x * scale);
        o[1] = (bf16_t)(v[i].y * scale);
        o[2] = (bf16_t)(v[i].z * scale);
        o[3] = (bf16_t)(v[i].w * scale);
        dst[lane + 64 * i] = o;
    }
    if (lane == 0) { sumExp[row] = 0.f; posSum[row] = 0.f; }
}

// ---------------------------------------------------------------------------
// Kernel 2: fused symmetric  C = E·E^T / T -> exp -> masked row+col sums.
// 256x256 tiles, 8 waves (2M x 4N, 512 thr). QUAD-buffered BK=32 ring
// (4 x 32 KB = 128 KiB LDS), staging 3 K-tiles ahead; one counted vmcnt(8)
// per K-step (slack ~2.5 K-steps), 2 phases/K-step, 16 MFMA/phase.
// LDS swizzle: physical 16B unit = logical ^ (row&3) on both the pre-swizzled
// global source (linear global_load_lds dest) and the ds_read side.
// ---------------------------------------------------------------------------
__global__ __launch_bounds__(512, 2) void gemm_fused(const bf16_t* __restrict__ E,
                                                     const int* __restrict__ labels,
                                                     float* __restrict__ sumExp,
                                                     float* __restrict__ posSum) {
    __shared__ bf16_t As[4][256 * 32];   // 4 x 16 KB ring
    __shared__ bf16_t Bs[4][256 * 32];   // 4 x 16 KB ring  (total 128 KiB)

    // XCD-aware bijective swizzle (528 % 8 == 0)
    const int b0 = blockIdx.x;
    const int b  = (b0 & 7) * (NBLK / 8) + (b0 >> 3);

    // triangular decode: b -> (ti >= tj)
    int ti = (int)((sqrtf(8.0f * (float)b + 1.0f) - 1.0f) * 0.5f);
    while ((ti + 1) * (ti + 2) / 2 <= b) ++ti;
    while (ti * (ti + 1) / 2 > b) --ti;
    const int tj = b - ti * (ti + 1) / 2;
    const bool isDiag = (ti == tj);

    const int tid  = threadIdx.x;
    const int wave = tid >> 6;
    const int lane = tid & 63;
    const int lr   = lane & 15;
    const int q    = lane >> 4;
    const int wm   = wave >> 2;     // 0..1 : 128-row half
    const int wn   = wave & 3;      // 0..3 : 64-col strip
    const int rowStart = ti * BM;
    const int colStart = tj * BM;

    f32x4 acc[8][4];
    #pragma unroll
    for (int m = 0; m < 8; ++m)
        #pragma unroll
        for (int n = 0; n < 4; ++n) acc[m][n] = {0.f, 0.f, 0.f, 0.f};

    // ---- staging geometry: 512 threads x 16 B = 8 KB = rows 0-127 of a
    // 256x32 panel; second gload covers rows 128-255. Phys unit tid -> row
    // r=tid>>2, unit tid&3; logical unit (tid&3)^(r&3) (inverse-swizzled
    // global source, linear LDS dest).
    const int r0  = tid >> 2;                    // 0..127
    const int lu0 = (tid & 3) ^ (r0 & 3);
    const char* gA = (const char*)(E + (size_t)rowStart * D) + (size_t)r0 * (D * 2) + lu0 * 16;
    const char* gB = (const char*)(E + (size_t)colStart * D) + (size_t)r0 * (D * 2) + lu0 * 16;

    #define STAGE_A2(bi, kb) do {                                                        \
        const char* g_ = gA + (kb);                                                      \
        char* l_ = (char*)&As[bi][0] + wave * 1024;                                      \
        __builtin_amdgcn_global_load_lds((const __attribute__((address_space(1))) void*)g_, \
            (__attribute__((address_space(3))) void*)l_, 16, 0, 0);                      \
        __builtin_amdgcn_global_load_lds(                                                \
            (const __attribute__((address_space(1))) void*)(g_ + 128 * 2048),            \
            (__attribute__((address_space(3))) void*)(l_ + 8192), 16, 0, 0);             \
    } while (0)
    #define STAGE_B2(bi, kb) do {                                                        \
        const char* g_ = gB + (kb);                                                      \
        char* l_ = (char*)&Bs[bi][0] + wave * 1024;                                      \
        __builtin_amdgcn_global_load_lds((const __attribute__((address_space(1))) void*)g_, \
            (__attribute__((address_space(3))) void*)l_, 16, 0, 0);                      \
        __builtin_amdgcn_global_load_lds(                                                \
            (const __attribute__((address_space(1))) void*)(g_ + 128 * 2048),            \
            (__attribute__((address_space(3))) void*)(l_ + 8192), 16, 0, 0);             \
    } while (0)

    // ---- frag reads. Row stride 64 B (32 cols). A rows: wm*128 + m*16 + lr;
    // B rows: wn*64 + n*16 + lr. Unit = q, phys = q ^ (lr&3) (row offsets are
    // multiples of 4 rows -> XOR term depends only on lr).
    const int su = (q ^ (lr & 3)) * 16;

    #define LD4(DST, RBASE, OFFB) do {                                                   \
        _Pragma("unroll")                                                                \
        for (int i_ = 0; i_ < 4; ++i_)                                                   \
            DST[i_] = *(const bf16x8*)((RBASE) + (OFFB) + i_ * 1024 + su);               \
    } while (0)
    #define MFMA16(AF, BF, MO) do {                                                      \
        _Pragma("unroll")                                                                \
        for (int m_ = 0; m_ < 4; ++m_) {                                                 \
            _Pragma("unroll")                                                            \
            for (int n_ = 0; n_ < 4; ++n_)                                               \
                acc[(MO) + m_][n_] = __builtin_amdgcn_mfma_f32_16x16x32_bf16(            \
                    AF[m_], BF[n_], acc[(MO) + m_][n_], 0, 0, 0);                        \
        }                                                                                \
    } while (0)
    #define PHASE_MID() do {                                                             \
        __builtin_amdgcn_s_barrier();                                                    \
        asm volatile("s_waitcnt lgkmcnt(0)");                                            \
        __builtin_amdgcn_sched_barrier(0);                                               \
        __builtin_amdgcn_s_setprio(1);                                                   \
    } while (0)
    #define PHASE_END() do {                                                             \
        __builtin_amdgcn_s_setprio(0);                                                   \
        __builtin_amdgcn_s_barrier();                                                    \
    } while (0)

    bf16x8 af[4], bfr[4];

    // ---- prologue: stage K-tiles 0,1,2 (12 loads). vmcnt(8) drains tile 0;
    // tiles 1,2 (8 loads) stay in flight.
    STAGE_A2(0, 0);   STAGE_B2(0, 0);
    STAGE_A2(1, 64);  STAGE_B2(1, 64);
    STAGE_A2(2, 128); STAGE_B2(2, 128);
    asm volatile("s_waitcnt vmcnt(8)" ::: "memory");
    __builtin_amdgcn_sched_barrier(0);
    __builtin_amdgcn_s_barrier();

    #pragma unroll 1
    for (int s = 0; s < KSTEPS; ++s) {
        const int bi   = s & 3;
        const int bnxt = (s + 3) & 3;          // ring slot freed at end of step s-1
        const int kb   = (s + 3) * 64;         // byte col offset of staged K-tile
        const bool doStage = (s <= KSTEPS - 4);
        const char* aBase = (const char*)&As[bi][0] + (wm * 128 + lr) * 64;
        const char* bBase = (const char*)&Bs[bi][0] + (wn * 64 + lr) * 64;

        // phase A: MFMA m0-3 | read A m0-3 + B n0-3 | stage next A panel
        LD4(af,  aBase, 0);
        LD4(bfr, bBase, 0);
        if (doStage) STAGE_A2(bnxt, kb);
        PHASE_MID();
        MFMA16(af, bfr, 0);
        PHASE_END();

        // phase B: MFMA m4-7 | read A m4-7 | stage next B panel | counted wait
        LD4(af, aBase, 4096);
        if (doStage) STAGE_B2(bnxt, kb);
        // drain the K-tile needed next step; keep 2-3 K-tiles in flight.
        if (s <= KSTEPS - 4)      asm volatile("s_waitcnt vmcnt(8)" ::: "memory");
        else if (s == KSTEPS - 3) asm volatile("s_waitcnt vmcnt(4)" ::: "memory");
        else                      asm volatile("s_waitcnt vmcnt(0)" ::: "memory");
        __builtin_amdgcn_sched_barrier(0);
        PHASE_MID();
        MFMA16(af, bfr, 4);
        PHASE_END();
    }

    // ---- epilogue: C/D layout col=lane&15, row=q*4+e (m89/m91).
    // Labels read straight from global (L2-resident, once per block).
    const float invT = 1.0f / 0.07f;
    int lc[4];
    #pragma unroll
    for (int n = 0; n < 4; ++n)
        lc[n] = labels[colStart + wn * 64 + n * 16 + lr];

    float colAll[4] = {0.f, 0.f, 0.f, 0.f};
    float colPos[4] = {0.f, 0.f, 0.f, 0.f};
    #pragma unroll
    for (int m = 0; m < 8; ++m) {
        #pragma unroll
        for (int e = 0; e < 4; ++e) {
            const int rloc = wm * 128 + m * 16 + q * 4 + e;
            const int gi   = rowStart + rloc;
            const int li   = labels[gi];
            float s_all = 0.f, s_pos = 0.f;
            #pragma unroll
            for (int n = 0; n < 4; ++n) {
                const int cloc = wn * 64 + n * 16 + lr;
                const int gj   = colStart + cloc;
                const float v  = __expf(acc[m][n][e] * invT);
                const bool same = (lc[n] == li);
                s_all += v;
                if (same && gi != gj) s_pos += v;
                if (!isDiag) {            // wave-uniform branch
                    colAll[n] += v;       // gi != gj guaranteed off-diagonal
                    if (same) colPos[n] += v;
                }
            }
            #pragma unroll
            for (int off = 1; off < 16; off <<= 1) {
                s_all += __shfl_xor(s_all, off, 64);
                s_pos += __shfl_xor(s_pos, off, 64);
            }
            if (lr == 0) {
                atomicAdd(&sumExp[gi], s_all);
                atomicAdd(&posSum[gi], s_pos);
            }
        }
    }
    if (!isDiag) {
        #pragma unroll
        for (int n = 0; n < 4; ++n) {
            float a = colAll[n], p = colPos[n];
            a += __shfl_xor(a, 16, 64);  a += __shfl_xor(a, 32, 64);
            p += __shfl_xor(p, 16, 64);  p += __shfl_xor(p, 32, 64);
            if (q == 0) {
                const int gj = colStart + wn * 64 + n * 16 + lr;
                atomicAdd(&sumExp[gj], a);
                atomicAdd(&posSum[gj], p);
            }
        }
    }
}

// ---------------------------------------------------------------------------
// Kernel 3: loss_i = log(sumExp_i / posSum_i); out = mean(loss).
// ---------------------------------------------------------------------------
__global__ __launch_bounds__(1024) void finalize(const float* __restrict__ sumExp,
                                                 const float* __restrict__ posSum,
                                                 float* __restrict__ out) {
    const int tid = threadIdx.x;
    float s = 0.f;
    #pragma unroll
    for (int i = tid; i < N; i += 1024)
        s += __logf(sumExp[i] / posSum[i]);
    #pragma unroll
    for (int off = 32; off >= 1; off >>= 1) s += __shfl_xor(s, off, 64);
    __shared__ float red[16];
    if ((tid & 63) == 0) red[tid >> 6] = s;
    __syncthreads();
    if (tid == 0) {
        float t = 0.f;
        #pragma unroll
        for (int i = 0; i < 16; ++i) t += red[i];
        out[0] = t / (float)N;
    }
}

extern "C" void kernel_launch(void* const* d_in, const int* in_sizes, int n_in,
                              void* d_out, int out_size, void* d_ws, size_t ws_size,
                              hipStream_t stream) {
    const float* emb    = (const float*)d_in[0];
    const int*   labels = (const int*)d_in[1];
    float* out = (float*)d_out;

    // ws layout: [sumExp: N floats][posSum: N floats][EN: N*D bf16]
    float*  sumExp = (float*)d_ws;
    float*  posSum = sumExp + N;
    bf16_t* EN     = (bf16_t*)((char*)d_ws + (size_t)2 * N * sizeof(float));

    norm_cast<<<N / 4, 256, 0, stream>>>(emb, EN, sumExp, posSum);

    gemm_fused<<<NBLK, 512, 0, stream>>>(EN, labels, sumExp, posSum);

    finalize<<<1, 1024, 0, stream>>>(sumExp, posSum, out);
}

// Round 5
// 222.744 us; speedup vs baseline: 1.2436x; 1.0287x over previous
//
#include <hip/hip_runtime.h>
#include <hip/hip_bf16.h>
#include <math.h>

#define N 8192
#define D 1024
#define BM 256
#define BK 64
#define NTIL 32                         // 8192/256
#define NBLK 528                        // 32*33/2 lower-tri tiles
#define ITERS 8                         // 16 K-tiles / 2 per iteration

typedef __bf16 bf16_t;
typedef bf16_t bf16x4 __attribute__((ext_vector_type(4)));
typedef bf16_t bf16x8 __attribute__((ext_vector_type(8)));
typedef float f32x4 __attribute__((ext_vector_type(4)));

// ---------------------------------------------------------------------------
// Kernel 1: L2-normalize each row, cast to bf16. Wave-per-row (no LDS, no
// __syncthreads). Also zeroes sumExp/posSum (replaces the memset dispatch).
// ---------------------------------------------------------------------------
__global__ __launch_bounds__(256) void norm_cast(const float* __restrict__ in,
                                                 bf16_t* __restrict__ out,
                                                 float* __restrict__ sumExp,
                                                 float* __restrict__ posSum) {
    const int wave = threadIdx.x >> 6, lane = threadIdx.x & 63;
    const int row  = blockIdx.x * 4 + wave;
    const float4* src = (const float4*)(in + (size_t)row * D);
    float4 v[4];
    float ss = 0.f;
    #pragma unroll
    for (int i = 0; i < 4; ++i) {
        v[i] = src[lane + 64 * i];
        ss += v[i].x * v[i].x + v[i].y * v[i].y + v[i].z * v[i].z + v[i].w * v[i].w;
    }
    #pragma unroll
    for (int off = 32; off >= 1; off >>= 1) ss += __shfl_xor(ss, off, 64);
    const float scale = 1.0f / fmaxf(sqrtf(ss), 1e-12f);
    bf16x4* dst = (bf16x4*)(out + (size_t)row * D);
    #pragma unroll
    for (int i = 0; i < 4; ++i) {
        bf16x4 o;
        o[0] = (bf16_t)(v[i].x * scale);
        o[1] = (bf16_t)(v[i].y * scale);
        o[2] = (bf16_t)(v[i].z * scale);
        o[3] = (bf16_t)(v[i].w * scale);
        dst[lane + 64 * i] = o;
    }
    if (lane == 0) { sumExp[row] = 0.f; posSum[row] = 0.f; }
}

// ---------------------------------------------------------------------------
// Kernel 2: fused symmetric  C = E·E^T / T -> exp -> masked row+col sums.
// 256x256 tiles, BK=64, 8 waves (2M x 4N), 8-phase schedule (2 K-tiles/iter),
// counted vmcnt(4) at phases 4/8, double-buffered LDS = exactly 128 KiB.
// SWIZZLE (the R5 experiment): pair-preserving 32B-chunk XOR. Each 128-B LDS
// row = 4 chunks of 32B; phys chunk = logical chunk ^ (row&3); 16B-pair order
// inside a chunk preserved. Staging keeps the LDS destination linear
// (global_load_lds requirement) and applies the inverse permutation to the
// GLOBAL source at 32B granularity (coalescer-friendly: each 8-lane row-group
// covers one whole 128B line in 32B-contiguous pairs). Frag reads use the
// same XOR; exactly 8 lanes per 16B bank-granule -> conflict-free.
// ---------------------------------------------------------------------------
__global__ __launch_bounds__(512, 2) void gemm_fused(const bf16_t* __restrict__ E,
                                                     const int* __restrict__ labels,
                                                     float* __restrict__ sumExp,
                                                     float* __restrict__ posSum) {
    __shared__ bf16_t As[2][2][128 * 64];   // [buf][half(rows 0-127 / 128-255)][...]
    __shared__ bf16_t Bs[2][2][128 * 64];   // [buf][half(cols 0-127 / 128-255)][...]
    // total static LDS: 131072 B

    // XCD-aware bijective swizzle (528 % 8 == 0)
    const int b0 = blockIdx.x;
    const int b  = (b0 & 7) * (NBLK / 8) + (b0 >> 3);

    // triangular decode: b -> (ti >= tj)
    int ti = (int)((sqrtf(8.0f * (float)b + 1.0f) - 1.0f) * 0.5f);
    while ((ti + 1) * (ti + 2) / 2 <= b) ++ti;
    while (ti * (ti + 1) / 2 > b) --ti;
    const int tj = b - ti * (ti + 1) / 2;
    const bool isDiag = (ti == tj);

    const int tid  = threadIdx.x;
    const int wave = tid >> 6;
    const int lane = tid & 63;
    const int lr   = lane & 15;
    const int q    = lane >> 4;
    const int wm   = wave >> 2;     // 0..1 : row half
    const int wn   = wave & 3;      // 0..3 : 64-col strip
    const int rowStart = ti * BM;
    const int colStart = tj * BM;

    f32x4 acc[8][4];
    #pragma unroll
    for (int m = 0; m < 8; ++m)
        #pragma unroll
        for (int n = 0; n < 4; ++n) acc[m][n] = {0.f, 0.f, 0.f, 0.f};

    // ---- staging geometry: thread covers linear 16B units (p*512 + tid) of a
    // 128x64 half-tile. Phys unit u -> row r=u>>3, unit-in-row j=u&7.
    // Logical unit j' = ((chunk ^ (r&3))<<1) | pair, chunk=j>>1, pair=j&1.
    const int r0  = tid >> 3;                    // 0..63 (second load adds 64 rows)
    const int j0  = tid & 7;
    const int lu0 = ((((j0 >> 1) ^ (r0 & 3)) << 1) | (j0 & 1));
    const char* gA = (const char*)(E + (size_t)rowStart * D) + (size_t)r0 * (D * 2) + lu0 * 16;
    const char* gB = (const char*)(E + (size_t)colStart * D) + (size_t)r0 * (D * 2) + lu0 * 16;

    #define STAGE_A(buf, h, kb) do {                                                     \
        const char* g0_ = gA + (size_t)(h) * (128 * 2048) + (kb);                        \
        char* l0_ = (char*)&As[buf][h][0] + wave * 1024;                                 \
        __builtin_amdgcn_global_load_lds((const __attribute__((address_space(1))) void*)g0_, \
            (__attribute__((address_space(3))) void*)l0_, 16, 0, 0);                     \
        __builtin_amdgcn_global_load_lds(                                                \
            (const __attribute__((address_space(1))) void*)(g0_ + 64 * 2048),            \
            (__attribute__((address_space(3))) void*)(l0_ + 8192), 16, 0, 0);            \
    } while (0)
    #define STAGE_B(buf, h, kb) do {                                                     \
        const char* g0_ = gB + (size_t)(h) * (128 * 2048) + (kb);                        \
        char* l0_ = (char*)&Bs[buf][h][0] + wave * 1024;                                 \
        __builtin_amdgcn_global_load_lds((const __attribute__((address_space(1))) void*)g0_, \
            (__attribute__((address_space(3))) void*)l0_, 16, 0, 0);                     \
        __builtin_amdgcn_global_load_lds(                                                \
            (const __attribute__((address_space(1))) void*)(g0_ + 64 * 2048),            \
            (__attribute__((address_space(3))) void*)(l0_ + 8192), 16, 0, 0);            \
    } while (0)

    // ---- frag-read offsets. Lane wants logical col-bytes k*64 + q*16..+15 of
    // row (...+lr): logical chunk = k*2 + (q>>1), pair = q&1; phys byte =
    // ((chunk ^ (lr&3))<<5) | (pair<<4)  (row offsets are multiples of 4 rows
    // -> r&3 == lr&3). 8 lanes per bank-granule per read: conflict-free.
    const int qh = q >> 1, qb = q & 1, r4 = lr & 3;
    const int su0 = (((0 | qh) ^ r4) << 5) | (qb << 4);     // k = 0
    const int su1 = (((2 | qh) ^ r4) << 5) | (qb << 4);     // k = 1
    const char* rA0 = (const char*)&As[0][wm][0] + lr * 128;
    const char* rA1 = (const char*)&As[1][wm][0] + lr * 128;
    const char* rB0 = (const char*)&Bs[0][wn >> 1][0] + (wn & 1) * 8192 + lr * 128;
    const char* rB1 = (const char*)&Bs[1][wn >> 1][0] + (wn & 1) * 8192 + lr * 128;

    #define LD_A4(DST, RBASE, MOFFB, SU) do {                                            \
        _Pragma("unroll")                                                                \
        for (int m_ = 0; m_ < 4; ++m_)                                                   \
            DST[m_] = *(const bf16x8*)((RBASE) + (MOFFB) + m_ * 2048 + (SU));            \
    } while (0)
    #define LD_B4(DST, RBASE, SU) do {                                                   \
        _Pragma("unroll")                                                                \
        for (int n_ = 0; n_ < 4; ++n_)                                                   \
            DST[n_] = *(const bf16x8*)((RBASE) + n_ * 2048 + (SU));                      \
    } while (0)
    #define MFMA_QUAD(AF, BF, MO) do {                                                   \
        _Pragma("unroll")                                                                \
        for (int m_ = 0; m_ < 4; ++m_) {                                                 \
            _Pragma("unroll")                                                            \
            for (int n_ = 0; n_ < 4; ++n_)                                               \
                acc[(MO) + m_][n_] = __builtin_amdgcn_mfma_f32_16x16x32_bf16(            \
                    AF[m_], BF[n_], acc[(MO) + m_][n_], 0, 0, 0);                        \
        }                                                                                \
    } while (0)
    #define PHASE_MID() do {                                                             \
        __builtin_amdgcn_s_barrier();                                                    \
        asm volatile("s_waitcnt lgkmcnt(0)");                                            \
        __builtin_amdgcn_sched_barrier(0);                                               \
        __builtin_amdgcn_s_setprio(1);                                                   \
    } while (0)
    #define PHASE_END() do {                                                             \
        __builtin_amdgcn_s_setprio(0);                                                   \
        __builtin_amdgcn_s_barrier();                                                    \
    } while (0)

    bf16x8 a0[4], a1[4], bq0[4], bq1[4];

    // ---- prologue: buf0 (K-tile 0) fully + buf1.B (K-tile 1). 12 loads;
    // vmcnt(4) -> buf0's 8 landed, buf1.B's 4 stay in flight.
    STAGE_B(0, 0, 0);  STAGE_B(0, 1, 0);
    STAGE_A(0, 0, 0);  STAGE_A(0, 1, 0);
    STAGE_B(1, 0, 128); STAGE_B(1, 1, 128);
    asm volatile("s_waitcnt vmcnt(4)" ::: "memory");
    __builtin_amdgcn_sched_barrier(0);
    __builtin_amdgcn_s_barrier();

    #pragma unroll 1
    for (int it = 0; it < ITERS; ++it) {
        const bool lastIt = (it == ITERS - 1);
        const int kb1 = (2 * it + 1) * 128;   // buf1's K-tile (byte col offset)
        const int kb2 = (2 * it + 2) * 128;   // next buf0 K-tile
        const int kb3 = (2 * it + 3) * 128;   // next buf1 K-tile

        // phase 1: buf0, m0-3, k0 | stage buf1.A h0 (this iter's second tile)
        LD_A4(a0, rA0, 0, su0);
        LD_B4(bq0, rB0, su0);
        STAGE_A(1, 0, kb1);
        PHASE_MID();
        MFMA_QUAD(a0, bq0, 0);
        PHASE_END();

        // phase 2: buf0, m0-3, k1 | stage buf1.A h1
        LD_A4(a1, rA0, 0, su1);
        LD_B4(bq1, rB0, su1);
        STAGE_A(1, 1, kb1);
        PHASE_MID();
        MFMA_QUAD(a1, bq1, 0);
        PHASE_END();

        // phase 3: buf0, m4-7, k0 | stage buf0.B h0 (K-tile 2it+2)
        LD_A4(a0, rA0, 8192, su0);
        if (!lastIt) STAGE_B(0, 0, kb2);
        PHASE_MID();
        MFMA_QUAD(a0, bq0, 4);
        PHASE_END();

        // phase 4: buf0, m4-7, k1 | stage buf0.B h1 | counted vmcnt:
        // waits the oldest 8 = buf1.A (ph1/2) + buf1.B (prev ph7/8 or prologue)
        LD_A4(a1, rA0, 8192, su1);
        if (!lastIt) {
            STAGE_B(0, 1, kb2);
            asm volatile("s_waitcnt vmcnt(4)" ::: "memory");
        } else {
            asm volatile("s_waitcnt vmcnt(0)" ::: "memory");
        }
        __builtin_amdgcn_sched_barrier(0);
        PHASE_MID();
        MFMA_QUAD(a1, bq1, 4);
        PHASE_END();

        // phase 5: buf1, m0-3, k0 | stage buf0.A h0
        LD_A4(a0, rA1, 0, su0);
        LD_B4(bq0, rB1, su0);
        if (!lastIt) STAGE_A(0, 0, kb2);
        PHASE_MID();
        MFMA_QUAD(a0, bq0, 0);
        PHASE_END();

        // phase 6: buf1, m0-3, k1 | stage buf0.A h1
        LD_A4(a1, rA1, 0, su1);
        LD_B4(bq1, rB1, su1);
        if (!lastIt) STAGE_A(0, 1, kb2);
        PHASE_MID();
        MFMA_QUAD(a1, bq1, 0);
        PHASE_END();

        // phase 7: buf1, m4-7, k0 | stage buf1.B h0 (K-tile 2it+3)
        LD_A4(a0, rA1, 8192, su0);
        if (!lastIt) STAGE_B(1, 0, kb3);
        PHASE_MID();
        MFMA_QUAD(a0, bq0, 4);
        PHASE_END();

        // phase 8: buf1, m4-7, k1 | stage buf1.B h1 | counted vmcnt:
        // waits the oldest 8 = buf0.B (ph3/4) + buf0.A (ph5/6)
        LD_A4(a1, rA1, 8192, su1);
        if (!lastIt) {
            STAGE_B(1, 1, kb3);
            asm volatile("s_waitcnt vmcnt(4)" ::: "memory");
            __builtin_amdgcn_sched_barrier(0);
        }
        PHASE_MID();
        MFMA_QUAD(a1, bq1, 4);
        PHASE_END();
    }

    // ---- epilogue: C/D layout col=lane&15, row=q*4+e (m89/m91).
    // Labels read straight from global (L2-resident, once per block).
    const float invT = 1.0f / 0.07f;
    int lc[4];
    #pragma unroll
    for (int n = 0; n < 4; ++n)
        lc[n] = labels[colStart + wn * 64 + n * 16 + lr];

    float colAll[4] = {0.f, 0.f, 0.f, 0.f};
    float colPos[4] = {0.f, 0.f, 0.f, 0.f};
    #pragma unroll
    for (int m = 0; m < 8; ++m) {
        #pragma unroll
        for (int e = 0; e < 4; ++e) {
            const int rloc = wm * 128 + m * 16 + q * 4 + e;
            const int gi   = rowStart + rloc;
            const int li   = labels[gi];
            float s_all = 0.f, s_pos = 0.f;
            #pragma unroll
            for (int n = 0; n < 4; ++n) {
                const int cloc = wn * 64 + n * 16 + lr;
                const int gj   = colStart + cloc;
                const float v  = __expf(acc[m][n][e] * invT);
                const bool same = (lc[n] == li);
                s_all += v;
                if (same && gi != gj) s_pos += v;
                if (!isDiag) {            // wave-uniform branch
                    colAll[n] += v;       // gi != gj guaranteed off-diagonal
                    if (same) colPos[n] += v;
                }
            }
            #pragma unroll
            for (int off = 1; off < 16; off <<= 1) {
                s_all += __shfl_xor(s_all, off, 64);
                s_pos += __shfl_xor(s_pos, off, 64);
            }
            if (lr == 0) {
                atomicAdd(&sumExp[gi], s_all);
                atomicAdd(&posSum[gi], s_pos);
            }
        }
    }
    if (!isDiag) {
        #pragma unroll
        for (int n = 0; n < 4; ++n) {
            float a = colAll[n], p = colPos[n];
            a += __shfl_xor(a, 16, 64);  a += __shfl_xor(a, 32, 64);
            p += __shfl_xor(p, 16, 64);  p += __shfl_xor(p, 32, 64);
            if (q == 0) {
                const int gj = colStart + wn * 64 + n * 16 + lr;
                atomicAdd(&sumExp[gj], a);
                atomicAdd(&posSum[gj], p);
            }
        }
    }
}

// ---------------------------------------------------------------------------
// Kernel 3: loss_i = log(sumExp_i / posSum_i); out = mean(loss).
// ---------------------------------------------------------------------------
__global__ __launch_bounds__(1024) void finalize(const float* __restrict__ sumExp,
                                                 const float* __restrict__ posSum,
                                                 float* __restrict__ out) {
    const int tid = threadIdx.x;
    float s = 0.f;
    #pragma unroll
    for (int i = tid; i < N; i += 1024)
        s += __logf(sumExp[i] / posSum[i]);
    #pragma unroll
    for (int off = 32; off >= 1; off >>= 1) s += __shfl_xor(s, off, 64);
    __shared__ float red[16];
    if ((tid & 63) == 0) red[tid >> 6] = s;
    __syncthreads();
    if (tid == 0) {
        float t = 0.f;
        #pragma unroll
        for (int i = 0; i < 16; ++i) t += red[i];
        out[0] = t / (float)N;
    }
}

extern "C" void kernel_launch(void* const* d_in, const int* in_sizes, int n_in,
                              void* d_out, int out_size, void* d_ws, size_t ws_size,
                              hipStream_t stream) {
    const float* emb    = (const float*)d_in[0];
    const int*   labels = (const int*)d_in[1];
    float* out = (float*)d_out;

    // ws layout: [sumExp: N floats][posSum: N floats][EN: N*D bf16]
    float*  sumExp = (float*)d_ws;
    float*  posSum = sumExp + N;
    bf16_t* EN     = (bf16_t*)((char*)d_ws + (size_t)2 * N * sizeof(float));

    norm_cast<<<N / 4, 256, 0, stream>>>(emb, EN, sumExp, posSum);

    gemm_fused<<<NBLK, 512, 0, stream>>>(EN, labels, sumExp, posSum);

    finalize<<<1, 1024, 0, stream>>>(sumExp, posSum, out);
}